// Round 2
// baseline (170.101 us; speedup 1.0000x reference)
//
#include <hip/hip_runtime.h>

#define HQ 32
#define HKV 8
#define DH 128
#define WIN 256
#define META 128
#define QSCALE 0.1275174324f    // rsqrt(128) * log2(e)  (scores produced in log2 space)
#define NFREQ 0.20762050594046f // log2(10000)/64: invfreq(i) = exp2(-NFREQ*i)
#define INV2PI 0.15915494309189535f

typedef __attribute__((ext_vector_type(8))) __bf16 bf16x8;
typedef __attribute__((ext_vector_type(4))) float f32x4;
typedef unsigned short u16;
typedef unsigned int u32;

__device__ __forceinline__ u16 f2bf(float f) {
  u32 u = __float_as_uint(f);
  u += 0x7FFFu + ((u >> 16) & 1u);
  return (u16)(u >> 16);
}
__device__ __forceinline__ u32 packbf(float a, float b) {  // a->lo16, b->hi16
  u32 ua = __float_as_uint(a); ua += 0x7FFFu + ((ua >> 16) & 1u);
  u32 ub = __float_as_uint(b); ub += 0x7FFFu + ((ub >> 16) & 1u);
  return (ua >> 16) | (ub & 0xFFFF0000u);
}

// HW trig: v_sin/v_cos take REVOLUTIONS; reduce to [0,1) with v_fract first.
// angle error vs f32-radian reference ~1.3e-4 rad << bf16 quantization 4e-3.
__device__ __forceinline__ void hw_sincos(float pos, float iv_rev, float* s, float* c) {
  float a = __builtin_amdgcn_fractf(pos * iv_rev);
  *s = __builtin_amdgcn_sinf(a);
  *c = __builtin_amdgcn_cosf(a);
}

// ---------- prep: RoPE(K) -> Kr[hk][s][d] bf16 ; V -> Vt[hk][d][s] bf16 ----------
// hk==0 blocks also emit the cos/sin table (f32x2 [s][64]) consumed by attn's Q RoPE.
// Trig via hardware v_sin/v_cos (libm __sincosf was the suspected time sink).
__global__ __launch_bounds__(256)
void prep_kv(const float* __restrict__ Kg, const float* __restrict__ Vg,
             u16* __restrict__ Kr, u16* __restrict__ Vt, float2* __restrict__ Tab,
             int S) {
  __shared__ float T[32][132];
  const int hk = blockIdx.x;
  const int s0 = blockIdx.y * 32;
  const int tid = threadIdx.x;
  {
    const int r = tid >> 3, c0 = (tid & 7) * 8;
    const int s = s0 + r;
    const float pos = (float)s;
    const float* src = Kg + ((size_t)s * HKV + hk) * DH;
    u16* dst = Kr + ((size_t)hk * S + s) * DH;
    float x[8], y[8];
    #pragma unroll
    for (int j = 0; j < 8; j += 4) {
      *(float4*)&x[j] = *(const float4*)(src + c0 + j);
      *(float4*)&y[j] = *(const float4*)(src + c0 + 64 + j);
    }
    u16 lo[8], hb[8];
    #pragma unroll
    for (int j = 0; j < 8; ++j) {
      float iv = __builtin_amdgcn_exp2f(-NFREQ * (float)(c0 + j)) * INV2PI;
      float sv, cv; hw_sincos(pos, iv, &sv, &cv);
      if (hk == 0) Tab[(size_t)s * 64 + c0 + j] = make_float2(cv, sv);
      lo[j] = f2bf(x[j] * cv - y[j] * sv);
      hb[j] = f2bf(y[j] * cv + x[j] * sv);
    }
    *(int4*)(dst + c0)      = *(int4*)&lo[0];
    *(int4*)(dst + c0 + 64) = *(int4*)&hb[0];
  }
  {
    const int r = tid >> 3, c = (tid & 7) * 16;
    const float* src = Vg + ((size_t)(s0 + r) * HKV + hk) * DH + c;
    #pragma unroll
    for (int j = 0; j < 16; j += 4) *(float4*)&T[r][c + j] = *(const float4*)(src + j);
  }
  __syncthreads();
  {
    const int d = tid >> 1, hf = (tid & 1) * 16;
    u16 buf[16];
    #pragma unroll
    for (int i = 0; i < 16; ++i) buf[i] = f2bf(T[hf + i][d]);
    u16* dst = Vt + ((size_t)hk * DH + d) * S + s0 + hf;
    *(int4*)(dst)     = *(int4*)&buf[0];
    *(int4*)(dst + 8) = *(int4*)&buf[8];
  }
}

// V register prefetch (named scalars; no arrays: alloca trap).
// 256 threads: V tile 128 d-rows x 64 kv (tid>>1 row, 4x int4).
#define LOAD_V(kv0_) do {                                                  \
    const int4* vs_ = (const int4*)(Vb + (kv0_));                          \
    fv0 = vs_[0]; fv1 = vs_[1]; fv2 = vs_[2]; fv3 = vs_[3];                \
  } while (0)

#define STORE_V() do {                                                     \
    int4* vd_ = (int4*)&Vs[tid >> 1][(tid & 1) * 32];                      \
    vd_[0] = fv0; vd_[1] = fv1; vd_[2] = fv2; vd_[3] = fv3;                \
  } while (0)

// ---------- main: flash attention, S^T/O^T, 16 q-rows per wave (16x16x32 MFMA) ----------
// 4 waves / 64 q-rows per block, grid 32x34 = 1088 blocks.
// K-tile A-frags load DIRECTLY from Kr (L2-resident, dense 64B-line pattern) -> no Ks
// LDS buffer, no K staging. LDS per block-tile drops ~320KB -> ~110KB (the r1 post-mortem
// identified the LDS pipe burst volume as the structural cost; K reads move to L2+L1 pipe).
// LDS 27648 B: Vs 18432 + Ps 9216 (Q prologue overlays). 4-5 blocks/CU by LDS; VGPR<=128.
__global__ __launch_bounds__(256, 4)
void attn_main(const float* __restrict__ Qg, const u16* __restrict__ Kr,
               const u16* __restrict__ Vt, const float2* __restrict__ Tab,
               float* __restrict__ Og, int S) {
  const int h = blockIdx.x;
  const int nqb = gridDim.y;
  const int q0 = (nqb - 1 - (int)blockIdx.y) * 64;   // heavy blocks first
  const int hk = h >> 2;
  const int tid = threadIdx.x;
  const int lane = tid & 63;
  const int wave = tid >> 6;       // 0..3
  const int qid  = lane & 15;      // q col within wave tile (C/D n-index)
  const int quad = lane >> 4;      // 0..3
  const int k8   = quad * 8;       // A/B-frag k offset within a 32-chunk

  __shared__ __align__(16) char smem[27648];
  u16 (*Qs)[136] = (u16(*)[136])smem;            // 64 x 136 (prologue overlay, 17408 B)
  u16 (*Vs)[72]  = (u16(*)[72])smem;             // 128 x 72 (18432 B)
  u16 (*Ps)[72]  = (u16(*)[72])(smem + 18432);   // 64 x 72, row = wave*16 + qid

  // per-lane K base: A-frag element K[kv0+16T+qid][k8 + 32c]
  const u16* Kq = Kr + (size_t)hk * S * DH + (size_t)qid * DH + k8;
  const u16* Vb = Vt + ((size_t)hk * DH + (tid >> 1)) * S + (tid & 1) * 32;

  int4 fv0, fv1, fv2, fv3;
  LOAD_V(0);   // tile-0 V loads fly during the Q prologue

  // ---- prologue: stage Q (64 rows) with table-RoPE * QSCALE ----
  {
    const int r = tid >> 2, c0 = (tid & 3) * 16;
    const int s = q0 + r;
    const float* qrow = Qg + ((size_t)s * HQ + h) * DH;
    const float2* tb = Tab + (size_t)s * 64 + c0;
    float x[16], y[16];
    float2 t[16];
    #pragma unroll
    for (int j = 0; j < 16; j += 4) {
      *(float4*)&x[j] = *(const float4*)(qrow + c0 + j);
      *(float4*)&y[j] = *(const float4*)(qrow + c0 + 64 + j);
    }
    #pragma unroll
    for (int j = 0; j < 16; j += 2) *(float4*)&t[j] = *(const float4*)(tb + j);
    u16 lo[16], hb[16];
    #pragma unroll
    for (int j = 0; j < 16; ++j) {
      lo[j] = f2bf((x[j] * t[j].x - y[j] * t[j].y) * QSCALE);
      hb[j] = f2bf((y[j] * t[j].x + x[j] * t[j].y) * QSCALE);
    }
    *(int4*)(&Qs[r][c0])      = *(int4*)&lo[0];
    *(int4*)(&Qs[r][c0 + 8])  = *(int4*)&lo[8];
    *(int4*)(&Qs[r][c0 + 64]) = *(int4*)&hb[0];
    *(int4*)(&Qs[r][c0 + 72]) = *(int4*)&hb[8];
  }
  __syncthreads();
  const int qw0 = q0 + wave * 16;
  const int q   = qw0 + qid;          // this lane's q row
  bf16x8 qa[4];                       // B-frags: Q[q][32c + k8 + j]
  {
    const u16* qb = &Qs[wave * 16 + qid][k8];
    #pragma unroll
    for (int c = 0; c < 4; ++c) qa[c] = *(const bf16x8*)(qb + 32 * c);
  }
  __syncthreads();   // Qs dead; region becomes Vs/Ps
  STORE_V();         // tile 0 -> LDS
  __syncthreads();

  int wstart = q0 - WIN; if (wstart < META) wstart = META;
  int nwin = (q0 + 64 - wstart) >> 6; if (nwin < 0) nwin = 0;
  const int ntiles = 2 + nwin;        // meta tiles first

  f32x4 acc[8];                       // O^T: acc[D], d = 16D + 4*quad + r, col q
  #pragma unroll
  for (int D = 0; D < 8; ++D)
    #pragma unroll
    for (int r = 0; r < 4; ++r) acc[D][r] = 0.f;
  float m_i = -1e30f, l_i = 0.f;      // l_i is a quad-partial; combined in epilogue

  for (int t = 0; t < ntiles; ++t) {
    const int kv0 = (t < 2) ? t * 64 : wstart + (t - 2) * 64;
    const bool haveNext = (t + 1 < ntiles);
    if (haveNext) {
      const int kvn = (t + 1 < 2) ? (t + 1) * 64 : wstart + (t - 1) * 64;
      LOAD_V(kvn);
    }

    const bool active = (kv0 <= qw0 + 15) &&
                        ((kv0 < META) || (qw0 - kv0 - 63 <= WIN));
    if (active) {
      // ---- S^T = K Q^T : 4 16x16 C-tiles over kv; K A-frags direct from L2 ----
      const u16* kt = Kq + (size_t)kv0 * DH;
      f32x4 sv[4];
      #pragma unroll
      for (int T = 0; T < 4; ++T)
        #pragma unroll
        for (int r = 0; r < 4; ++r) sv[T][r] = 0.f;
      #pragma unroll
      for (int T = 0; T < 4; ++T) {
        const u16* kp = kt + (size_t)T * 16 * DH;
        int4 kA = *(const int4*)(kp);
        int4 kB = *(const int4*)(kp + 32);
        int4 kC = *(const int4*)(kp + 64);
        int4 kD = *(const int4*)(kp + 96);
        sv[T] = __builtin_amdgcn_mfma_f32_16x16x32_bf16(*(const bf16x8*)&kA, qa[0], sv[T], 0, 0, 0);
        sv[T] = __builtin_amdgcn_mfma_f32_16x16x32_bf16(*(const bf16x8*)&kB, qa[1], sv[T], 0, 0, 0);
        sv[T] = __builtin_amdgcn_mfma_f32_16x16x32_bf16(*(const bf16x8*)&kC, qa[2], sv[T], 0, 0, 0);
        sv[T] = __builtin_amdgcn_mfma_f32_16x16x32_bf16(*(const bf16x8*)&kD, qa[3], sv[T], 0, 0, 0);
      }

      // ---- mask (per element: kv = kv0 + 16T + 4*quad + r) ----
      const bool fullv = (kv0 + 63 <= qw0) &&
                         ((kv0 + 63 < META) || (qw0 + 15 - kv0 <= WIN));
      if (!fullv) {
        #pragma unroll
        for (int T = 0; T < 4; ++T) {
          #pragma unroll
          for (int r = 0; r < 4; ++r) {
            const int kv = kv0 + 16 * T + 4 * quad + r;
            if (!((kv <= q) && (((q - kv) <= WIN) || (kv < META)))) sv[T][r] = -1e30f;
          }
        }
      }

      // ---- online softmax: reg reduce + 2 cross-quad shuffles for max ----
      float mx = -1e30f;
      #pragma unroll
      for (int T = 0; T < 4; ++T)
        #pragma unroll
        for (int r = 0; r < 4; ++r) mx = fmaxf(mx, sv[T][r]);
      mx = fmaxf(mx, __shfl_xor(mx, 16));
      mx = fmaxf(mx, __shfl_xor(mx, 32));
      const float mnew = fmaxf(m_i, mx);
      const float al = __builtin_amdgcn_exp2f(m_i - mnew);
      m_i = mnew;
      float ps = 0.f;
      #pragma unroll
      for (int T = 0; T < 4; ++T)
        #pragma unroll
        for (int r = 0; r < 4; ++r) {
          sv[T][r] = __builtin_amdgcn_exp2f(sv[T][r] - mnew);
          ps += sv[T][r];
        }
      l_i = l_i * al + ps;            // quad-partial sum (m shared => consistent)
      #pragma unroll
      for (int D = 0; D < 8; ++D)
        #pragma unroll
        for (int r = 0; r < 4; ++r) acc[D][r] *= al;

      // ---- P: C-layout -> B-layout via wave-private LDS (in-order, no barrier) ----
      {
        int2* pw = (int2*)&Ps[wave * 16 + qid][0];
        #pragma unroll
        for (int T = 0; T < 4; ++T) {
          int2 pr;
          pr.x = (int)packbf(sv[T][0], sv[T][1]);
          pr.y = (int)packbf(sv[T][2], sv[T][3]);
          pw[4 * T + quad] = pr;
        }
      }
      const u16* pb = &Ps[wave * 16 + qid][k8];
      const bf16x8 p0 = *(const bf16x8*)(pb);        // kv chunk 0 (0..31)
      const bf16x8 p1 = *(const bf16x8*)(pb + 32);   // kv chunk 1 (32..63)

      // ---- O^T += V^T P^T : 8 d-tiles x 2 kv-chunks ----
      #pragma unroll
      for (int D = 0; D < 8; ++D) {
        const u16* va = &Vs[16 * D + qid][k8];
        acc[D] = __builtin_amdgcn_mfma_f32_16x16x32_bf16(*(const bf16x8*)(va),      p0, acc[D], 0, 0, 0);
        acc[D] = __builtin_amdgcn_mfma_f32_16x16x32_bf16(*(const bf16x8*)(va + 32), p1, acc[D], 0, 0, 0);
      }
    }

    if (haveNext) {
      __syncthreads();   // all waves done reading Vs
      STORE_V();         // prefetched tile -> LDS
      __syncthreads();
    }
  }

  // ---- epilogue: combine quad-partial l, scale, 16B stores ----
  l_i += __shfl_xor(l_i, 16);
  l_i += __shfl_xor(l_i, 32);
  const float inv = 1.0f / l_i;
  float* ob = Og + ((size_t)q * HQ + h) * DH;
  #pragma unroll
  for (int D = 0; D < 8; ++D) {       // d = 16D + 4*quad + {0..3}
    float4 o = { acc[D][0] * inv, acc[D][1] * inv, acc[D][2] * inv, acc[D][3] * inv };
    *(float4*)(ob + 16 * D + 4 * quad) = o;
  }
}

extern "C" void kernel_launch(void* const* d_in, const int* in_sizes, int n_in,
                              void* d_out, int out_size, void* d_ws, size_t ws_size,
                              hipStream_t stream) {
  const float* Qg = (const float*)d_in[0];
  const float* Kg = (const float*)d_in[1];
  const float* Vg = (const float*)d_in[2];
  float* Og = (float*)d_out;
  const int S = in_sizes[0] / (HQ * DH);   // 2176

  u16* Kr = (u16*)d_ws;                                            // 4.45 MB
  u16* Vt = (u16*)((char*)d_ws + (size_t)HKV * S * DH * 2);        // 4.45 MB
  float2* Tab = (float2*)((char*)d_ws + (size_t)HKV * S * DH * 4); // 1.11 MB cos/sin table

  prep_kv<<<dim3(HKV, S / 32), dim3(256), 0, stream>>>(Kg, Vg, Kr, Vt, Tab, S);
  attn_main<<<dim3(HQ, S / 64), dim3(256), 0, stream>>>(Qg, Kr, Vt, Tab, Og, S);
}

// Round 3
// 148.811 us; speedup vs baseline: 1.1431x; 1.1431x over previous
//
#include <hip/hip_runtime.h>

#define HQ 32
#define HKV 8
#define DH 128
#define WIN 256
#define META 128
#define QSCALE 0.1275174324f    // rsqrt(128) * log2(e)  (scores produced in log2 space)
#define NFREQ 0.20762050594046f // log2(10000)/64: invfreq(i) = exp2(-NFREQ*i)
#define INV2PI 0.15915494309189535f

typedef __attribute__((ext_vector_type(8))) __bf16 bf16x8;
typedef __attribute__((ext_vector_type(4))) float f32x4;
typedef unsigned short u16;
typedef unsigned int u32;

__device__ __forceinline__ u16 f2bf(float f) {
  u32 u = __float_as_uint(f);
  u += 0x7FFFu + ((u >> 16) & 1u);
  return (u16)(u >> 16);
}
__device__ __forceinline__ u32 packbf(float a, float b) {  // a->lo16, b->hi16
  u32 ua = __float_as_uint(a); ua += 0x7FFFu + ((ua >> 16) & 1u);
  u32 ub = __float_as_uint(b); ub += 0x7FFFu + ((ub >> 16) & 1u);
  return (ua >> 16) | (ub & 0xFFFF0000u);
}

// HW trig: v_sin/v_cos take REVOLUTIONS; reduce with v_fract.
// angle error ~1.3e-4 rad << bf16 quantization 4e-3.
__device__ __forceinline__ void hw_sincos(float pos, float iv_rev, float* s, float* c) {
  float a = __builtin_amdgcn_fractf(pos * iv_rev);
  *s = __builtin_amdgcn_sinf(a);
  *c = __builtin_amdgcn_cosf(a);
}

// ---------- prep: RoPE(K) -> Kr[hk][s][d] bf16 ; V -> Vt[hk][d][s] bf16 ----------
// hk==0 blocks also emit the cos/sin table (f32x2 [s][64]) for attn's Q RoPE.
__global__ __launch_bounds__(256)
void prep_kv(const float* __restrict__ Kg, const float* __restrict__ Vg,
             u16* __restrict__ Kr, u16* __restrict__ Vt, float2* __restrict__ Tab,
             int S) {
  __shared__ float T[32][132];
  const int hk = blockIdx.x;
  const int s0 = blockIdx.y * 32;
  const int tid = threadIdx.x;
  {
    const int r = tid >> 3, c0 = (tid & 7) * 8;
    const int s = s0 + r;
    const float pos = (float)s;
    const float* src = Kg + ((size_t)s * HKV + hk) * DH;
    u16* dst = Kr + ((size_t)hk * S + s) * DH;
    float x[8], y[8];
    #pragma unroll
    for (int j = 0; j < 8; j += 4) {
      *(float4*)&x[j] = *(const float4*)(src + c0 + j);
      *(float4*)&y[j] = *(const float4*)(src + c0 + 64 + j);
    }
    u16 lo[8], hb[8];
    #pragma unroll
    for (int j = 0; j < 8; ++j) {
      float iv = __builtin_amdgcn_exp2f(-NFREQ * (float)(c0 + j)) * INV2PI;
      float sv, cv; hw_sincos(pos, iv, &sv, &cv);
      if (hk == 0) Tab[(size_t)s * 64 + c0 + j] = make_float2(cv, sv);
      lo[j] = f2bf(x[j] * cv - y[j] * sv);
      hb[j] = f2bf(y[j] * cv + x[j] * sv);
    }
    *(int4*)(dst + c0)      = *(int4*)&lo[0];
    *(int4*)(dst + c0 + 64) = *(int4*)&hb[0];
  }
  {
    const int r = tid >> 3, c = (tid & 7) * 16;
    const float* src = Vg + ((size_t)(s0 + r) * HKV + hk) * DH + c;
    #pragma unroll
    for (int j = 0; j < 16; j += 4) *(float4*)&T[r][c + j] = *(const float4*)(src + j);
  }
  __syncthreads();
  {
    const int d = tid >> 1, hf = (tid & 1) * 16;
    u16 buf[16];
    #pragma unroll
    for (int i = 0; i < 16; ++i) buf[i] = f2bf(T[hf + i][d]);
    u16* dst = Vt + ((size_t)hk * DH + d) * S + s0 + hf;
    *(int4*)(dst)     = *(int4*)&buf[0];
    *(int4*)(dst + 8) = *(int4*)&buf[8];
  }
}

// ---- register prefetch of next KV tile (named scalars; no arrays: alloca trap) ----
#define LOAD_KV(kv0_) do {                                                   \
    const int4* ks_ = (const int4*)(Kb + (size_t)((kv0_) + kr) * DH + ka4 * 32); \
    fk0 = ks_[0]; fk1 = ks_[1]; fk2 = ks_[2]; fk3 = ks_[3];                  \
    const int4* vs_ = (const int4*)(Vb + (kv0_));                            \
    fv0 = vs_[0]; fv1 = vs_[1]; fv2 = vs_[2]; fv3 = vs_[3];                  \
  } while (0)

// swizzled 16B-slot addresses: phys_slot = slot ^ (row & 7)  (T2-style, replaces +8 pad)
#define KSLOT(j_) (smem + kr * 256 + ((((ka4 << 2) + (j_)) ^ (kr & 7)) << 4))
#define VSLOT(j_) (Vbase + vr * 128 + ((((vh << 2) + (j_)) ^ (vr & 7)) << 4))
#define STORE_KV() do {                                                      \
    *(int4*)KSLOT(0) = fk0; *(int4*)KSLOT(1) = fk1;                          \
    *(int4*)KSLOT(2) = fk2; *(int4*)KSLOT(3) = fk3;                          \
    *(int4*)VSLOT(0) = fv0; *(int4*)VSLOT(1) = fv1;                          \
    *(int4*)VSLOT(2) = fv2; *(int4*)VSLOT(3) = fv3;                          \
  } while (0)

// ---------- main: flash attention, S^T/O^T, 16 q-rows per wave (16x16x32 MFMA) ----------
// 4 waves / 64 q-rows per block, grid 32x34 = 1088 blocks.
// LDS 40960 B via XOR-swizzle instead of +8 row pads:
//   Ks 64x256B @0, Vs 128x128B @16384, Ps 64x128B @32768 (Q prologue overlays Ks).
//   40960 x 4 = 163840 = exactly 160 KiB -> 4 blocks/CU (was 3 at 45056 padded),
//   occupancy cap 12 -> 16 waves/CU. Swizzle: phys 16B-slot = logical ^ (row&7),
//   same bank spreading as the pad (2-way max on b128 frag reads).
// Softmax defer-max (T13): scores are log2-space; skip O-rescale while
//   __all(mx - m_i <= 8) -> P bounded by 2^8, bf16 relative error unchanged.
__global__ __launch_bounds__(256, 4)
void attn_main(const float* __restrict__ Qg, const u16* __restrict__ Kr,
               const u16* __restrict__ Vt, const float2* __restrict__ Tab,
               float* __restrict__ Og, int S) {
  const int h = blockIdx.x;
  const int nqb = gridDim.y;
  const int q0 = (nqb - 1 - (int)blockIdx.y) * 64;   // heavy blocks first
  const int hk = h >> 2;
  const int tid = threadIdx.x;
  const int lane = tid & 63;
  const int wave = tid >> 6;       // 0..3
  const int qid  = lane & 15;      // q col within wave tile (C/D n-index)
  const int quad = lane >> 4;      // 0..3
  const int swz  = qid & 7;        // row-XOR for fragment reads

  __shared__ __align__(16) char smem[40960];
  char* const Vbase = smem + 16384;
  char* const Pbase = smem + 32768;

  const u16* Kb = Kr + (size_t)hk * S * DH;
  const u16* Vb = Vt + ((size_t)hk * DH + (tid >> 1)) * S + (tid & 1) * 32;
  const int kr = tid >> 2, ka4 = tid & 3;   // K stage: row, quarter (64B each)
  const int vr = tid >> 1, vh  = tid & 1;   // V stage: row (=d), half (64B each)

  int4 fk0, fk1, fk2, fk3, fv0, fv1, fv2, fv3;
  LOAD_KV(0);   // tile-0 loads fly during the Q prologue

  // ---- prologue: stage Q (64 rows) with table-RoPE * QSCALE, swizzled ----
  {
    const int r = tid >> 2, a = tid & 3, c0 = a * 16;
    const int s = q0 + r;
    const float* qrow = Qg + ((size_t)s * HQ + h) * DH;
    const float2* tb = Tab + (size_t)s * 64 + c0;
    float x[16], y[16];
    float2 t[16];
    #pragma unroll
    for (int j = 0; j < 16; j += 4) {
      *(float4*)&x[j] = *(const float4*)(qrow + c0 + j);
      *(float4*)&y[j] = *(const float4*)(qrow + c0 + 64 + j);
    }
    #pragma unroll
    for (int j = 0; j < 16; j += 2) *(float4*)&t[j] = *(const float4*)(tb + j);
    u16 lo[16], hb[16];
    #pragma unroll
    for (int j = 0; j < 16; ++j) {
      lo[j] = f2bf((x[j] * t[j].x - y[j] * t[j].y) * QSCALE);
      hb[j] = f2bf((y[j] * t[j].x + x[j] * t[j].y) * QSCALE);
    }
    char* qd = smem + r * 256;
    *(int4*)(qd + (((2 * a)     ^ (r & 7)) << 4)) = *(int4*)&lo[0];
    *(int4*)(qd + (((2 * a + 1) ^ (r & 7)) << 4)) = *(int4*)&lo[8];
    *(int4*)(qd + (((2 * a + 8) ^ (r & 7)) << 4)) = *(int4*)&hb[0];
    *(int4*)(qd + (((2 * a + 9) ^ (r & 7)) << 4)) = *(int4*)&hb[8];
  }
  __syncthreads();
  const int qw0 = q0 + wave * 16;
  const int q   = qw0 + qid;          // this lane's q row
  bf16x8 qa[4];                       // B-frags: Q[q][32c + 8*quad + j]
  {
    const char* qb = smem + (wave * 16 + qid) * 256;
    #pragma unroll
    for (int c = 0; c < 4; ++c)
      qa[c] = *(const bf16x8*)(qb + ((((c << 2) + quad) ^ swz) << 4));
  }
  __syncthreads();   // Qs dead; region becomes Ks
  STORE_KV();        // tile 0 -> LDS
  __syncthreads();

  int wstart = q0 - WIN; if (wstart < META) wstart = META;
  int nwin = (q0 + 64 - wstart) >> 6; if (nwin < 0) nwin = 0;
  const int ntiles = 2 + nwin;        // meta tiles first

  f32x4 acc[8];                       // O^T: acc[D], d = 16D + 4*quad + r, col q
  #pragma unroll
  for (int D = 0; D < 8; ++D)
    #pragma unroll
    for (int r = 0; r < 4; ++r) acc[D][r] = 0.f;
  float m_i = -1e30f, l_i = 0.f;      // l_i is a quad-partial; combined in epilogue

  for (int t = 0; t < ntiles; ++t) {
    const int kv0 = (t < 2) ? t * 64 : wstart + (t - 2) * 64;
    const bool haveNext = (t + 1 < ntiles);
    if (haveNext) {
      const int kvn = (t + 1 < 2) ? (t + 1) * 64 : wstart + (t - 1) * 64;
      LOAD_KV(kvn);
    }

    const bool active = (kv0 <= qw0 + 15) &&
                        ((kv0 < META) || (qw0 - kv0 - 63 <= WIN));
    if (active) {
      // ---- S^T = K Q^T : 4 16x16 C-tiles over kv, K=128 in 4 chunks ----
      f32x4 sv[4];
      #pragma unroll
      for (int T = 0; T < 4; ++T)
        #pragma unroll
        for (int r = 0; r < 4; ++r) sv[T][r] = 0.f;
      #pragma unroll
      for (int T = 0; T < 4; ++T) {
        const char* ka = smem + (16 * T + qid) * 256;
        #pragma unroll
        for (int c = 0; c < 4; ++c)
          sv[T] = __builtin_amdgcn_mfma_f32_16x16x32_bf16(
                    *(const bf16x8*)(ka + ((((c << 2) + quad) ^ swz) << 4)),
                    qa[c], sv[T], 0, 0, 0);
      }

      // ---- mask (per element: kv = kv0 + 16T + 4*quad + r) ----
      const bool fullv = (kv0 + 63 <= qw0) &&
                         ((kv0 + 63 < META) || (qw0 + 15 - kv0 <= WIN));
      if (!fullv) {
        #pragma unroll
        for (int T = 0; T < 4; ++T) {
          #pragma unroll
          for (int r = 0; r < 4; ++r) {
            const int kv = kv0 + 16 * T + 4 * quad + r;
            if (!((kv <= q) && (((q - kv) <= WIN) || (kv < META)))) sv[T][r] = -1e30f;
          }
        }
      }

      // ---- online softmax: reg reduce + 2 cross-quad shuffles for max ----
      float mx = -1e30f;
      #pragma unroll
      for (int T = 0; T < 4; ++T)
        #pragma unroll
        for (int r = 0; r < 4; ++r) mx = fmaxf(mx, sv[T][r]);
      mx = fmaxf(mx, __shfl_xor(mx, 16));
      mx = fmaxf(mx, __shfl_xor(mx, 32));
      // defer-max (T13): only rescale when some row's max grew past 2^8 headroom
      if (!__all(mx - m_i <= 8.0f)) {
        const float mnew = fmaxf(m_i, mx);
        const float al = __builtin_amdgcn_exp2f(m_i - mnew);
        m_i = mnew;
        l_i *= al;
        #pragma unroll
        for (int D = 0; D < 8; ++D)
          #pragma unroll
          for (int r = 0; r < 4; ++r) acc[D][r] *= al;
      }
      float ps = 0.f;
      #pragma unroll
      for (int T = 0; T < 4; ++T)
        #pragma unroll
        for (int r = 0; r < 4; ++r) {
          sv[T][r] = __builtin_amdgcn_exp2f(sv[T][r] - m_i);
          ps += sv[T][r];
        }
      l_i += ps;                      // quad-partial sum (m shared => consistent)

      // ---- P: C-layout -> B-layout via wave-private LDS (in-order, no barrier) ----
      {
        char* pw = Pbase + (wave * 16 + qid) * 128;
        #pragma unroll
        for (int T = 0; T < 4; ++T) {
          int2 pr;
          pr.x = (int)packbf(sv[T][0], sv[T][1]);
          pr.y = (int)packbf(sv[T][2], sv[T][3]);
          *(int2*)(pw + ((((T << 1) + (quad >> 1)) ^ swz) << 4) + ((quad & 1) << 3)) = pr;
        }
      }
      const char* pb = Pbase + (wave * 16 + qid) * 128;
      const bf16x8 p0 = *(const bf16x8*)(pb + ((quad ^ swz) << 4));        // kv 0..31
      const bf16x8 p1 = *(const bf16x8*)(pb + (((4 + quad) ^ swz) << 4));  // kv 32..63

      // ---- O^T += V^T P^T : 8 d-tiles x 2 kv-chunks ----
      #pragma unroll
      for (int D = 0; D < 8; ++D) {
        const char* va = Vbase + (16 * D + qid) * 128;
        acc[D] = __builtin_amdgcn_mfma_f32_16x16x32_bf16(
                   *(const bf16x8*)(va + ((quad ^ swz) << 4)),       p0, acc[D], 0, 0, 0);
        acc[D] = __builtin_amdgcn_mfma_f32_16x16x32_bf16(
                   *(const bf16x8*)(va + (((4 + quad) ^ swz) << 4)), p1, acc[D], 0, 0, 0);
      }
    }

    if (haveNext) {
      __syncthreads();   // all waves done reading Ks/Vs
      STORE_KV();        // prefetched tile -> LDS
      __syncthreads();
    }
  }

  // ---- epilogue: combine quad-partial l, scale, 16B stores ----
  l_i += __shfl_xor(l_i, 16);
  l_i += __shfl_xor(l_i, 32);
  const float inv = 1.0f / l_i;
  float* ob = Og + ((size_t)q * HQ + h) * DH;
  #pragma unroll
  for (int D = 0; D < 8; ++D) {       // d = 16D + 4*quad + {0..3}
    float4 o = { acc[D][0] * inv, acc[D][1] * inv, acc[D][2] * inv, acc[D][3] * inv };
    *(float4*)(ob + 16 * D + 4 * quad) = o;
  }
}

extern "C" void kernel_launch(void* const* d_in, const int* in_sizes, int n_in,
                              void* d_out, int out_size, void* d_ws, size_t ws_size,
                              hipStream_t stream) {
  const float* Qg = (const float*)d_in[0];
  const float* Kg = (const float*)d_in[1];
  const float* Vg = (const float*)d_in[2];
  float* Og = (float*)d_out;
  const int S = in_sizes[0] / (HQ * DH);   // 2176

  u16* Kr = (u16*)d_ws;                                            // 4.45 MB
  u16* Vt = (u16*)((char*)d_ws + (size_t)HKV * S * DH * 2);        // 4.45 MB
  float2* Tab = (float2*)((char*)d_ws + (size_t)HKV * S * DH * 4); // 1.11 MB cos/sin table

  prep_kv<<<dim3(HKV, S / 32), dim3(256), 0, stream>>>(Kg, Vg, Kr, Vt, Tab, S);
  attn_main<<<dim3(HQ, S / 64), dim3(256), 0, stream>>>(Qg, Kr, Vt, Tab, Og, S);
}

// Round 4
// 144.942 us; speedup vs baseline: 1.1736x; 1.0267x over previous
//
#include <hip/hip_runtime.h>

#define HQ 32
#define HKV 8
#define DH 128
#define WIN 256
#define META 128
#define QSCALE 0.1275174324f    // rsqrt(128) * log2(e)  (scores produced in log2 space)
#define NFREQ 0.20762050594046f // log2(10000)/64: invfreq(i) = exp2(-NFREQ*i)
#define INV2PI 0.15915494309189535f

typedef __attribute__((ext_vector_type(8))) __bf16 bf16x8;
typedef __attribute__((ext_vector_type(4))) float f32x4;
typedef unsigned short u16;
typedef unsigned int u32;

__device__ __forceinline__ u16 f2bf(float f) {
  u32 u = __float_as_uint(f);
  u += 0x7FFFu + ((u >> 16) & 1u);
  return (u16)(u >> 16);
}
__device__ __forceinline__ u32 packbf(float a, float b) {  // a->lo16, b->hi16
  u32 ua = __float_as_uint(a); ua += 0x7FFFu + ((ua >> 16) & 1u);
  u32 ub = __float_as_uint(b); ub += 0x7FFFu + ((ub >> 16) & 1u);
  return (ua >> 16) | (ub & 0xFFFF0000u);
}

// HW trig: v_sin/v_cos take REVOLUTIONS; reduce with v_fract.
__device__ __forceinline__ void hw_sincos(float pos, float iv_rev, float* s, float* c) {
  float a = __builtin_amdgcn_fractf(pos * iv_rev);
  *s = __builtin_amdgcn_sinf(a);
  *c = __builtin_amdgcn_cosf(a);
}

// ---------- prep: RoPE(K) -> Kr[hk][s][d] bf16 ; V -> Vt[hk][d][s] bf16 ----------
__global__ __launch_bounds__(256)
void prep_kv(const float* __restrict__ Kg, const float* __restrict__ Vg,
             u16* __restrict__ Kr, u16* __restrict__ Vt, float2* __restrict__ Tab,
             int S) {
  __shared__ float T[32][132];
  const int hk = blockIdx.x;
  const int s0 = blockIdx.y * 32;
  const int tid = threadIdx.x;
  {
    const int r = tid >> 3, c0 = (tid & 7) * 8;
    const int s = s0 + r;
    const float pos = (float)s;
    const float* src = Kg + ((size_t)s * HKV + hk) * DH;
    u16* dst = Kr + ((size_t)hk * S + s) * DH;
    float x[8], y[8];
    #pragma unroll
    for (int j = 0; j < 8; j += 4) {
      *(float4*)&x[j] = *(const float4*)(src + c0 + j);
      *(float4*)&y[j] = *(const float4*)(src + c0 + 64 + j);
    }
    u16 lo[8], hb[8];
    #pragma unroll
    for (int j = 0; j < 8; ++j) {
      float iv = __builtin_amdgcn_exp2f(-NFREQ * (float)(c0 + j)) * INV2PI;
      float sv, cv; hw_sincos(pos, iv, &sv, &cv);
      if (hk == 0) Tab[(size_t)s * 64 + c0 + j] = make_float2(cv, sv);
      lo[j] = f2bf(x[j] * cv - y[j] * sv);
      hb[j] = f2bf(y[j] * cv + x[j] * sv);
    }
    *(int4*)(dst + c0)      = *(int4*)&lo[0];
    *(int4*)(dst + c0 + 64) = *(int4*)&hb[0];
  }
  {
    const int r = tid >> 3, c = (tid & 7) * 16;
    const float* src = Vg + ((size_t)(s0 + r) * HKV + hk) * DH + c;
    #pragma unroll
    for (int j = 0; j < 16; j += 4) *(float4*)&T[r][c + j] = *(const float4*)(src + j);
  }
  __syncthreads();
  {
    const int d = tid >> 1, hf = (tid & 1) * 16;
    u16 buf[16];
    #pragma unroll
    for (int i = 0; i < 16; ++i) buf[i] = f2bf(T[hf + i][d]);
    u16* dst = Vt + ((size_t)hk * DH + d) * S + s0 + hf;
    *(int4*)(dst)     = *(int4*)&buf[0];
    *(int4*)(dst + 8) = *(int4*)&buf[8];
  }
}

// ---- register prefetch of next 32-kv tile: 16 VGPRs total (was 32 at KVBLK=64) ----
// K: 32 rows x 256B, 8 thr/row x 32B.  V: 64 super-rows x 128B ([d][kv32] ++ [d+64][kv32]),
// 4 thr/row x 32B (each thread one contiguous 32B from Vt).
#define LOAD_KV(kv0_) do {                                                    \
    const int4* ks_ = (const int4*)(Kb + (size_t)((kv0_) + kr) * DH + a8 * 16); \
    fk0 = ks_[0]; fk1 = ks_[1];                                               \
    const int4* vs_ = (const int4*)(Vbs + (kv0_));                            \
    fv0 = vs_[0]; fv1 = vs_[1];                                               \
  } while (0)

// 16B-slot XOR swizzle: phys_slot = logical_slot ^ (row & 7). All reads/writes <=2-way.
#define KSLOT(j_) (Kre + kr * 256 + ((((a8 << 1) | (j_)) ^ (kr & 7)) << 4))
#define VSLOT(j_) (Vre + vr * 128 + ((((q4 << 1) | (j_)) ^ (vr & 7)) << 4))
#define STORE_KV() do {                                                       \
    *(int4*)KSLOT(0) = fk0; *(int4*)KSLOT(1) = fk1;                           \
    *(int4*)VSLOT(0) = fv0; *(int4*)VSLOT(1) = fv1;                           \
  } while (0)

// ---------- main: flash attention, S^T/O^T, 16 q-rows/wave, KVBLK=32 ----------
// 4 waves / 64 q-rows per block, grid 32x34 = 1088 blocks.
// KVBLK=32 halves the per-block footprint: LDS 20480 B (K 8K + V 8K + P 4K),
// staging regs 32->16, sv 16->8 => ~100 VGPR, NO launch-bounds cap (r3's spill
// trap: bound=4 forced 128-reg cap -> scratch = +10MB WRITE/+40MB FETCH).
// Occupancy ~5 blocks/CU (reg-bound) => all 1088 blocks resident in ONE round
// (<=1280 slots); makespan ~ heaviest block instead of ~2 block-generations.
// Narrow-tile bank conflicts fixed by super-row V/P layouts (128B rows) + swizzle.
__global__ __launch_bounds__(256)
void attn_main(const float* __restrict__ Qg, const u16* __restrict__ Kr,
               const u16* __restrict__ Vt, const float2* __restrict__ Tab,
               float* __restrict__ Og, int S) {
  const int h = blockIdx.x;
  const int nqb = gridDim.y;
  const int q0 = (nqb - 1 - (int)blockIdx.y) * 64;   // heavy blocks first
  const int hk = h >> 2;
  const int tid = threadIdx.x;
  const int lane = tid & 63;
  const int wave = tid >> 6;       // 0..3
  const int qid  = lane & 15;      // q col within wave tile (C/D n-index)
  const int quad = lane >> 4;      // 0..3
  const int swz  = qid & 7;        // row-XOR for fragment reads

  __shared__ __align__(16) char smem[20480];
  char* const Kre = smem;            // 32 rows x 256B = 8192
  char* const Vre = smem + 8192;     // 64 super-rows x 128B = 8192
  char* const Pba = smem + 16384;    // 4 waves x 1024B

  const u16* Kb = Kr + (size_t)hk * S * DH;
  const int kr = tid >> 3, a8 = tid & 7;   // K stage: row, 32B-eighth
  const int vr = tid >> 2, q4 = tid & 3;   // V stage: super-row, quarter
  const u16* Vbs = Vt + ((size_t)hk * DH + (vr + ((q4 >> 1) << 6))) * S + ((q4 & 1) << 4);

  int4 fk0, fk1, fv0, fv1;
  LOAD_KV(0);   // tile-0 loads fly during the Q prologue

  // ---- prologue: stage Q (64 rows x 256B, swizzled) with table-RoPE * QSCALE ----
  {
    const int r = tid >> 2, a = tid & 3, c0 = a * 16;
    const int s = q0 + r;
    const float* qrow = Qg + ((size_t)s * HQ + h) * DH;
    const float2* tb = Tab + (size_t)s * 64 + c0;
    float x[16], y[16];
    float2 t[16];
    #pragma unroll
    for (int j = 0; j < 16; j += 4) {
      *(float4*)&x[j] = *(const float4*)(qrow + c0 + j);
      *(float4*)&y[j] = *(const float4*)(qrow + c0 + 64 + j);
    }
    #pragma unroll
    for (int j = 0; j < 16; j += 2) *(float4*)&t[j] = *(const float4*)(tb + j);
    u16 lo[16], hb[16];
    #pragma unroll
    for (int j = 0; j < 16; ++j) {
      lo[j] = f2bf((x[j] * t[j].x - y[j] * t[j].y) * QSCALE);
      hb[j] = f2bf((y[j] * t[j].x + x[j] * t[j].y) * QSCALE);
    }
    char* qd = smem + r * 256;
    *(int4*)(qd + (((2 * a)     ^ (r & 7)) << 4)) = *(int4*)&lo[0];
    *(int4*)(qd + (((2 * a + 1) ^ (r & 7)) << 4)) = *(int4*)&lo[8];
    *(int4*)(qd + (((2 * a + 8) ^ (r & 7)) << 4)) = *(int4*)&hb[0];
    *(int4*)(qd + (((2 * a + 9) ^ (r & 7)) << 4)) = *(int4*)&hb[8];
  }
  __syncthreads();
  const int qw0 = q0 + wave * 16;
  const int q   = qw0 + qid;          // this lane's q row
  bf16x8 qa[4];                       // B-frags: Q[q][32c + 8*quad + j]
  {
    const char* qb = smem + (wave * 16 + qid) * 256;
    #pragma unroll
    for (int c = 0; c < 4; ++c)
      qa[c] = *(const bf16x8*)(qb + ((((c << 2) + quad) ^ swz) << 4));
  }
  __syncthreads();   // Qs dead; region becomes Ks/Vs
  STORE_KV();        // tile 0 -> LDS
  __syncthreads();

  // tiles of 32 kv: meta tiles (kv<128, causally reachable) then window tiles
  const int mt0 = (q0 + 64) >> 5;
  const int mt = mt0 < 4 ? mt0 : 4;
  int wstart = q0 - WIN; if (wstart < META) wstart = META;
  int nwin = (q0 + 64 - wstart) >> 5; if (nwin < 0) nwin = 0;
  const int ntiles = mt + nwin;

  f32x4 acc[8];                       // O^T: acc[D], d = 16D + 4*quad + r, col q
  #pragma unroll
  for (int D = 0; D < 8; ++D)
    #pragma unroll
    for (int r = 0; r < 4; ++r) acc[D][r] = 0.f;
  float m_i = -1e30f, l_i = 0.f;      // quad-partial l; combined in epilogue

  const int rp = qid & 7, hq = qid >> 3;   // P super-row coords
  char* const Pw = Pba + wave * 1024;

  for (int t = 0; t < ntiles; ++t) {
    const int kv0 = (t < mt) ? t * 32 : wstart + (t - mt) * 32;
    const bool haveNext = (t + 1 < ntiles);
    if (haveNext) {
      const int kvn = (t + 1 < mt) ? (t + 1) * 32 : wstart + (t + 1 - mt) * 32;
      LOAD_KV(kvn);
    }

    const bool active = (kv0 <= qw0 + 15) &&
                        ((kv0 < META) || (qw0 - kv0 - 31 <= WIN));
    if (active) {
      // ---- S^T = K Q^T : 2 16x16 C-tiles over kv, K=128 in 4 chunks ----
      f32x4 sv[2];
      #pragma unroll
      for (int T = 0; T < 2; ++T)
        #pragma unroll
        for (int r = 0; r < 4; ++r) sv[T][r] = 0.f;
      #pragma unroll
      for (int T = 0; T < 2; ++T) {
        const char* ka = Kre + (16 * T + qid) * 256;
        #pragma unroll
        for (int c = 0; c < 4; ++c)
          sv[T] = __builtin_amdgcn_mfma_f32_16x16x32_bf16(
                    *(const bf16x8*)(ka + ((((c << 2) + quad) ^ swz) << 4)),
                    qa[c], sv[T], 0, 0, 0);
      }

      // ---- mask (per element: kv = kv0 + 16T + 4*quad + r) ----
      const bool fullv = (kv0 + 31 <= qw0) &&
                         ((kv0 + 31 < META) || (qw0 + 15 - kv0 <= WIN));
      if (!fullv) {
        #pragma unroll
        for (int T = 0; T < 2; ++T) {
          #pragma unroll
          for (int r = 0; r < 4; ++r) {
            const int kv = kv0 + 16 * T + 4 * quad + r;
            if (!((kv <= q) && (((q - kv) <= WIN) || (kv < META)))) sv[T][r] = -1e30f;
          }
        }
      }

      // ---- online softmax: reg reduce + 2 cross-quad shuffles for max ----
      float mx = -1e30f;
      #pragma unroll
      for (int T = 0; T < 2; ++T)
        #pragma unroll
        for (int r = 0; r < 4; ++r) mx = fmaxf(mx, sv[T][r]);
      mx = fmaxf(mx, __shfl_xor(mx, 16));
      mx = fmaxf(mx, __shfl_xor(mx, 32));
      // defer-max (T13): rescale only when max grew past 2^8 headroom
      if (!__all(mx - m_i <= 8.0f)) {
        const float mnew = fmaxf(m_i, mx);
        const float al = __builtin_amdgcn_exp2f(m_i - mnew);
        m_i = mnew;
        l_i *= al;
        #pragma unroll
        for (int D = 0; D < 8; ++D)
          #pragma unroll
          for (int r = 0; r < 4; ++r) acc[D][r] *= al;
      }
      float ps = 0.f;
      #pragma unroll
      for (int T = 0; T < 2; ++T)
        #pragma unroll
        for (int r = 0; r < 4; ++r) {
          sv[T][r] = __builtin_amdgcn_exp2f(sv[T][r] - m_i);
          ps += sv[T][r];
        }
      l_i += ps;

      // ---- P: C->B layout via wave-private LDS super-rows (in-order, no barrier) ----
      // P row rp holds [q=rp][kv32] ++ [q=rp+8][kv32]; slot s = 4*hq + 2T + (quad>>1)
      #pragma unroll
      for (int T = 0; T < 2; ++T) {
        int2 pr;
        pr.x = (int)packbf(sv[T][0], sv[T][1]);
        pr.y = (int)packbf(sv[T][2], sv[T][3]);
        *(int2*)(Pw + rp * 128 + ((((hq << 2) + (T << 1) + (quad >> 1)) ^ rp) << 4)
                 + ((quad & 1) << 3)) = pr;
      }
      const bf16x8 p0 = *(const bf16x8*)(Pw + rp * 128 + ((((hq << 2) + quad) ^ rp) << 4));

      // ---- O^T += V^T P^T : 8 d-tiles x 1 kv-chunk ----
      #pragma unroll
      for (int D = 0; D < 8; ++D) {
        const char* va = Vre + (16 * (D & 3) + qid) * 128
                       + (((((D >> 2) << 2) + quad) ^ swz) << 4);
        acc[D] = __builtin_amdgcn_mfma_f32_16x16x32_bf16(*(const bf16x8*)va, p0, acc[D], 0, 0, 0);
      }
    }

    if (haveNext) {
      __syncthreads();   // all waves done reading Ks/Vs
      STORE_KV();        // prefetched tile -> LDS
      __syncthreads();
    }
  }

  // ---- epilogue: combine quad-partial l, scale, 16B stores ----
  l_i += __shfl_xor(l_i, 16);
  l_i += __shfl_xor(l_i, 32);
  const float inv = 1.0f / l_i;
  float* ob = Og + ((size_t)q * HQ + h) * DH;
  #pragma unroll
  for (int D = 0; D < 8; ++D) {       // d = 16D + 4*quad + {0..3}
    float4 o = { acc[D][0] * inv, acc[D][1] * inv, acc[D][2] * inv, acc[D][3] * inv };
    *(float4*)(ob + 16 * D + 4 * quad) = o;
  }
}

extern "C" void kernel_launch(void* const* d_in, const int* in_sizes, int n_in,
                              void* d_out, int out_size, void* d_ws, size_t ws_size,
                              hipStream_t stream) {
  const float* Qg = (const float*)d_in[0];
  const float* Kg = (const float*)d_in[1];
  const float* Vg = (const float*)d_in[2];
  float* Og = (float*)d_out;
  const int S = in_sizes[0] / (HQ * DH);   // 2176

  u16* Kr = (u16*)d_ws;                                            // 4.45 MB
  u16* Vt = (u16*)((char*)d_ws + (size_t)HKV * S * DH * 2);        // 4.45 MB
  float2* Tab = (float2*)((char*)d_ws + (size_t)HKV * S * DH * 4); // 1.11 MB cos/sin table

  prep_kv<<<dim3(HKV, S / 32), dim3(256), 0, stream>>>(Kg, Vg, Kr, Vt, Tab, S);
  attn_main<<<dim3(HQ, S / 64), dim3(256), 0, stream>>>(Qg, Kr, Vt, Tab, Og, S);
}

// Round 5
// 137.798 us; speedup vs baseline: 1.2344x; 1.0518x over previous
//
#include <hip/hip_runtime.h>

#define HQ 32
#define HKV 8
#define DH 128
#define WIN 256
#define META 128
#define QSCALE 0.1275174324f    // rsqrt(128) * log2(e)  (scores produced in log2 space)
#define NFREQ 0.20762050594046f // log2(10000)/64: invfreq(i) = exp2(-NFREQ*i)
#define INV2PI 0.15915494309189535f

typedef __attribute__((ext_vector_type(8))) __bf16 bf16x8;
typedef __attribute__((ext_vector_type(4))) float f32x4;
typedef unsigned short u16;
typedef unsigned int u32;

__device__ __forceinline__ u16 f2bf(float f) {
  u32 u = __float_as_uint(f);
  u += 0x7FFFu + ((u >> 16) & 1u);
  return (u16)(u >> 16);
}
__device__ __forceinline__ u32 packbf(float a, float b) {  // a->lo16, b->hi16
  u32 ua = __float_as_uint(a); ua += 0x7FFFu + ((ua >> 16) & 1u);
  u32 ub = __float_as_uint(b); ub += 0x7FFFu + ((ub >> 16) & 1u);
  return (ua >> 16) | (ub & 0xFFFF0000u);
}

// HW trig: v_sin/v_cos take REVOLUTIONS; reduce with v_fract.
// angle error ~1.3e-4 rad << bf16 quantization 4e-3.
__device__ __forceinline__ void hw_sincos(float pos, float iv_rev, float* s, float* c) {
  float a = __builtin_amdgcn_fractf(pos * iv_rev);
  *s = __builtin_amdgcn_sinf(a);
  *c = __builtin_amdgcn_cosf(a);
}

// ---------- prep: RoPE(K) -> Kr[hk][s][d] bf16 ; V -> Vt[hk][d][s] bf16 ----------
// hk==0 blocks also emit the cos/sin table (f32x2 [s][64]) for attn's Q RoPE.
__global__ __launch_bounds__(256)
void prep_kv(const float* __restrict__ Kg, const float* __restrict__ Vg,
             u16* __restrict__ Kr, u16* __restrict__ Vt, float2* __restrict__ Tab,
             int S) {
  __shared__ float T[32][132];
  const int hk = blockIdx.x;
  const int s0 = blockIdx.y * 32;
  const int tid = threadIdx.x;
  {
    const int r = tid >> 3, c0 = (tid & 7) * 8;
    const int s = s0 + r;
    const float pos = (float)s;
    const float* src = Kg + ((size_t)s * HKV + hk) * DH;
    u16* dst = Kr + ((size_t)hk * S + s) * DH;
    float x[8], y[8];
    #pragma unroll
    for (int j = 0; j < 8; j += 4) {
      *(float4*)&x[j] = *(const float4*)(src + c0 + j);
      *(float4*)&y[j] = *(const float4*)(src + c0 + 64 + j);
    }
    u16 lo[8], hb[8];
    #pragma unroll
    for (int j = 0; j < 8; ++j) {
      float iv = __builtin_amdgcn_exp2f(-NFREQ * (float)(c0 + j)) * INV2PI;
      float sv, cv; hw_sincos(pos, iv, &sv, &cv);
      if (hk == 0) Tab[(size_t)s * 64 + c0 + j] = make_float2(cv, sv);
      lo[j] = f2bf(x[j] * cv - y[j] * sv);
      hb[j] = f2bf(y[j] * cv + x[j] * sv);
    }
    *(int4*)(dst + c0)      = *(int4*)&lo[0];
    *(int4*)(dst + c0 + 64) = *(int4*)&hb[0];
  }
  {
    const int r = tid >> 3, c = (tid & 7) * 16;
    const float* src = Vg + ((size_t)(s0 + r) * HKV + hk) * DH + c;
    #pragma unroll
    for (int j = 0; j < 16; j += 4) *(float4*)&T[r][c + j] = *(const float4*)(src + j);
  }
  __syncthreads();
  {
    const int d = tid >> 1, hf = (tid & 1) * 16;
    u16 buf[16];
    #pragma unroll
    for (int i = 0; i < 16; ++i) buf[i] = f2bf(T[hf + i][d]);
    u16* dst = Vt + ((size_t)hk * DH + d) * S + s0 + hf;
    *(int4*)(dst)     = *(int4*)&buf[0];
    *(int4*)(dst + 8) = *(int4*)&buf[8];
  }
}

// ---- register prefetch of next KV tile (named scalars; no arrays: alloca trap) ----
#define LOAD_KV(kv0_) do {                                                   \
    const int4* ks_ = (const int4*)(Kb + (size_t)((kv0_) + kr) * DH + ka4 * 32); \
    fk0 = ks_[0]; fk1 = ks_[1]; fk2 = ks_[2]; fk3 = ks_[3];                  \
    const int4* vs_ = (const int4*)(Vb + (kv0_));                            \
    fv0 = vs_[0]; fv1 = vs_[1]; fv2 = vs_[2]; fv3 = vs_[3];                  \
  } while (0)

// swizzled 16B-slot addresses: phys_slot = slot ^ (row & 7)  (T2-style, replaces +8 pad)
#define KSLOT(j_) (smem + kr * 256 + ((((ka4 << 2) + (j_)) ^ (kr & 7)) << 4))
#define VSLOT(j_) (Vbase + vr * 128 + ((((vh << 2) + (j_)) ^ (vr & 7)) << 4))
#define STORE_KV() do {                                                      \
    *(int4*)KSLOT(0) = fk0; *(int4*)KSLOT(1) = fk1;                          \
    *(int4*)KSLOT(2) = fk2; *(int4*)KSLOT(3) = fk3;                          \
    *(int4*)VSLOT(0) = fv0; *(int4*)VSLOT(1) = fv1;                          \
    *(int4*)VSLOT(2) = fv2; *(int4*)VSLOT(3) = fv3;                          \
  } while (0)

// ---------- main: flash attention, S^T/O^T, 16 q-rows per wave (16x16x32 MFMA) ----------
// 4 waves / 64 q-rows per block, grid 32x34 = 1088 blocks, KVBLK=64.
// LDS 40960 B via XOR-swizzle (no pads): Ks 64x256B @0, Vs 128x128B @16384,
//   Ps 64x128B @32768 (Q prologue overlays Ks). 40960 x 4 = exactly 160 KiB
//   -> 4 blocks/CU, 16 waves/CU cap.
// NO __launch_bounds__ min-waves arg: r3's (256,4) meant 4 waves/EU (NOT blocks/CU),
//   capping unified regs at 128 -> 2 int4 of staging spilled, reloaded per tile
//   (+40MB FETCH / +8.6MB WRITE, +15us). Natural usage ~104 incl acc -> 4 waves/EU
//   without any cap.
// Softmax defer-max (T13): scores are log2-space; skip O-rescale while
//   __all(mx - m_i <= 8) -> P bounded by 2^8, bf16 relative error unchanged.
__global__ __launch_bounds__(256)
void attn_main(const float* __restrict__ Qg, const u16* __restrict__ Kr,
               const u16* __restrict__ Vt, const float2* __restrict__ Tab,
               float* __restrict__ Og, int S) {
  const int h = blockIdx.x;
  const int nqb = gridDim.y;
  const int q0 = (nqb - 1 - (int)blockIdx.y) * 64;   // heavy blocks first
  const int hk = h >> 2;
  const int tid = threadIdx.x;
  const int lane = tid & 63;
  const int wave = tid >> 6;       // 0..3
  const int qid  = lane & 15;      // q col within wave tile (C/D n-index)
  const int quad = lane >> 4;      // 0..3
  const int swz  = qid & 7;        // row-XOR for fragment reads

  __shared__ __align__(16) char smem[40960];
  char* const Vbase = smem + 16384;
  char* const Pbase = smem + 32768;

  const u16* Kb = Kr + (size_t)hk * S * DH;
  const u16* Vb = Vt + ((size_t)hk * DH + (tid >> 1)) * S + (tid & 1) * 32;
  const int kr = tid >> 2, ka4 = tid & 3;   // K stage: row, quarter (64B each)
  const int vr = tid >> 1, vh  = tid & 1;   // V stage: row (=d), half (64B each)

  int4 fk0, fk1, fk2, fk3, fv0, fv1, fv2, fv3;
  LOAD_KV(0);   // tile-0 loads fly during the Q prologue

  // ---- prologue: stage Q (64 rows) with table-RoPE * QSCALE, swizzled ----
  {
    const int r = tid >> 2, a = tid & 3, c0 = a * 16;
    const int s = q0 + r;
    const float* qrow = Qg + ((size_t)s * HQ + h) * DH;
    const float2* tb = Tab + (size_t)s * 64 + c0;
    float x[16], y[16];
    float2 t[16];
    #pragma unroll
    for (int j = 0; j < 16; j += 4) {
      *(float4*)&x[j] = *(const float4*)(qrow + c0 + j);
      *(float4*)&y[j] = *(const float4*)(qrow + c0 + 64 + j);
    }
    #pragma unroll
    for (int j = 0; j < 16; j += 2) *(float4*)&t[j] = *(const float4*)(tb + j);
    u16 lo[16], hb[16];
    #pragma unroll
    for (int j = 0; j < 16; ++j) {
      lo[j] = f2bf((x[j] * t[j].x - y[j] * t[j].y) * QSCALE);
      hb[j] = f2bf((y[j] * t[j].x + x[j] * t[j].y) * QSCALE);
    }
    char* qd = smem + r * 256;
    *(int4*)(qd + (((2 * a)     ^ (r & 7)) << 4)) = *(int4*)&lo[0];
    *(int4*)(qd + (((2 * a + 1) ^ (r & 7)) << 4)) = *(int4*)&lo[8];
    *(int4*)(qd + (((2 * a + 8) ^ (r & 7)) << 4)) = *(int4*)&hb[0];
    *(int4*)(qd + (((2 * a + 9) ^ (r & 7)) << 4)) = *(int4*)&hb[8];
  }
  __syncthreads();
  const int qw0 = q0 + wave * 16;
  const int q   = qw0 + qid;          // this lane's q row
  bf16x8 qa[4];                       // B-frags: Q[q][32c + 8*quad + j]
  {
    const char* qb = smem + (wave * 16 + qid) * 256;
    #pragma unroll
    for (int c = 0; c < 4; ++c)
      qa[c] = *(const bf16x8*)(qb + ((((c << 2) + quad) ^ swz) << 4));
  }
  __syncthreads();   // Qs dead; region becomes Ks
  STORE_KV();        // tile 0 -> LDS
  __syncthreads();

  int wstart = q0 - WIN; if (wstart < META) wstart = META;
  int nwin = (q0 + 64 - wstart) >> 6; if (nwin < 0) nwin = 0;
  const int ntiles = 2 + nwin;        // meta tiles first

  f32x4 acc[8];                       // O^T: acc[D], d = 16D + 4*quad + r, col q
  #pragma unroll
  for (int D = 0; D < 8; ++D)
    #pragma unroll
    for (int r = 0; r < 4; ++r) acc[D][r] = 0.f;
  float m_i = -1e30f, l_i = 0.f;      // l_i is a quad-partial; combined in epilogue

  for (int t = 0; t < ntiles; ++t) {
    const int kv0 = (t < 2) ? t * 64 : wstart + (t - 2) * 64;
    const bool haveNext = (t + 1 < ntiles);
    if (haveNext) {
      const int kvn = (t + 1 < 2) ? (t + 1) * 64 : wstart + (t - 1) * 64;
      LOAD_KV(kvn);
    }

    const bool active = (kv0 <= qw0 + 15) &&
                        ((kv0 < META) || (qw0 - kv0 - 63 <= WIN));
    if (active) {
      // ---- S^T = K Q^T : 4 16x16 C-tiles over kv, K=128 in 4 chunks ----
      f32x4 sv[4];
      #pragma unroll
      for (int T = 0; T < 4; ++T)
        #pragma unroll
        for (int r = 0; r < 4; ++r) sv[T][r] = 0.f;
      #pragma unroll
      for (int T = 0; T < 4; ++T) {
        const char* ka = smem + (16 * T + qid) * 256;
        #pragma unroll
        for (int c = 0; c < 4; ++c)
          sv[T] = __builtin_amdgcn_mfma_f32_16x16x32_bf16(
                    *(const bf16x8*)(ka + ((((c << 2) + quad) ^ swz) << 4)),
                    qa[c], sv[T], 0, 0, 0);
      }

      // ---- mask (per element: kv = kv0 + 16T + 4*quad + r) ----
      const bool fullv = (kv0 + 63 <= qw0) &&
                         ((kv0 + 63 < META) || (qw0 + 15 - kv0 <= WIN));
      if (!fullv) {
        #pragma unroll
        for (int T = 0; T < 4; ++T) {
          #pragma unroll
          for (int r = 0; r < 4; ++r) {
            const int kv = kv0 + 16 * T + 4 * quad + r;
            if (!((kv <= q) && (((q - kv) <= WIN) || (kv < META)))) sv[T][r] = -1e30f;
          }
        }
      }

      // ---- online softmax: reg reduce + 2 cross-quad shuffles for max ----
      float mx = -1e30f;
      #pragma unroll
      for (int T = 0; T < 4; ++T)
        #pragma unroll
        for (int r = 0; r < 4; ++r) mx = fmaxf(mx, sv[T][r]);
      mx = fmaxf(mx, __shfl_xor(mx, 16));
      mx = fmaxf(mx, __shfl_xor(mx, 32));
      // defer-max (T13): only rescale when some row's max grew past 2^8 headroom
      if (!__all(mx - m_i <= 8.0f)) {
        const float mnew = fmaxf(m_i, mx);
        const float al = __builtin_amdgcn_exp2f(m_i - mnew);
        m_i = mnew;
        l_i *= al;
        #pragma unroll
        for (int D = 0; D < 8; ++D)
          #pragma unroll
          for (int r = 0; r < 4; ++r) acc[D][r] *= al;
      }
      float ps = 0.f;
      #pragma unroll
      for (int T = 0; T < 4; ++T)
        #pragma unroll
        for (int r = 0; r < 4; ++r) {
          sv[T][r] = __builtin_amdgcn_exp2f(sv[T][r] - m_i);
          ps += sv[T][r];
        }
      l_i += ps;                      // quad-partial sum (m shared => consistent)

      // ---- P: C-layout -> B-layout via wave-private LDS (in-order, no barrier) ----
      {
        char* pw = Pbase + (wave * 16 + qid) * 128;
        #pragma unroll
        for (int T = 0; T < 4; ++T) {
          int2 pr;
          pr.x = (int)packbf(sv[T][0], sv[T][1]);
          pr.y = (int)packbf(sv[T][2], sv[T][3]);
          *(int2*)(pw + ((((T << 1) + (quad >> 1)) ^ swz) << 4) + ((quad & 1) << 3)) = pr;
        }
      }
      const char* pb = Pbase + (wave * 16 + qid) * 128;
      const bf16x8 p0 = *(const bf16x8*)(pb + ((quad ^ swz) << 4));        // kv 0..31
      const bf16x8 p1 = *(const bf16x8*)(pb + (((4 + quad) ^ swz) << 4));  // kv 32..63

      // ---- O^T += V^T P^T : 8 d-tiles x 2 kv-chunks ----
      #pragma unroll
      for (int D = 0; D < 8; ++D) {
        const char* va = Vbase + (16 * D + qid) * 128;
        acc[D] = __builtin_amdgcn_mfma_f32_16x16x32_bf16(
                   *(const bf16x8*)(va + ((quad ^ swz) << 4)),       p0, acc[D], 0, 0, 0);
        acc[D] = __builtin_amdgcn_mfma_f32_16x16x32_bf16(
                   *(const bf16x8*)(va + (((4 + quad) ^ swz) << 4)), p1, acc[D], 0, 0, 0);
      }
    }

    if (haveNext) {
      __syncthreads();   // all waves done reading Ks/Vs
      STORE_KV();        // prefetched tile -> LDS
      __syncthreads();
    }
  }

  // ---- epilogue: combine quad-partial l, scale, 16B stores ----
  l_i += __shfl_xor(l_i, 16);
  l_i += __shfl_xor(l_i, 32);
  const float inv = 1.0f / l_i;
  float* ob = Og + ((size_t)q * HQ + h) * DH;
  #pragma unroll
  for (int D = 0; D < 8; ++D) {       // d = 16D + 4*quad + {0..3}
    float4 o = { acc[D][0] * inv, acc[D][1] * inv, acc[D][2] * inv, acc[D][3] * inv };
    *(float4*)(ob + 16 * D + 4 * quad) = o;
  }
}

extern "C" void kernel_launch(void* const* d_in, const int* in_sizes, int n_in,
                              void* d_out, int out_size, void* d_ws, size_t ws_size,
                              hipStream_t stream) {
  const float* Qg = (const float*)d_in[0];
  const float* Kg = (const float*)d_in[1];
  const float* Vg = (const float*)d_in[2];
  float* Og = (float*)d_out;
  const int S = in_sizes[0] / (HQ * DH);   // 2176

  u16* Kr = (u16*)d_ws;                                            // 4.45 MB
  u16* Vt = (u16*)((char*)d_ws + (size_t)HKV * S * DH * 2);        // 4.45 MB
  float2* Tab = (float2*)((char*)d_ws + (size_t)HKV * S * DH * 4); // 1.11 MB cos/sin table

  prep_kv<<<dim3(HKV, S / 32), dim3(256), 0, stream>>>(Kg, Vg, Kr, Vt, Tab, S);
  attn_main<<<dim3(HQ, S / 64), dim3(256), 0, stream>>>(Qg, Kr, Vt, Tab, Og, S);
}